// Round 8
// baseline (134.106 us; speedup 1.0000x reference)
//
#include <hip/hip_runtime.h>
#include <math.h>

#define D 8
#define K 32
constexpr int BLOCK = 256;
constexpr int ROWS  = 4;                       // rows per thread
constexpr int GRID  = 2048;                    // GRID*BLOCK*ROWS == N
constexpr int NWAVE = BLOCK / 64;

typedef float vf4 __attribute__((ext_vector_type(4)));
typedef float v2f __attribute__((ext_vector_type(2)));

// numpy pairwise-sum tree for n=8: ((p0+p1)+(p2+p3))+((p4+p5)+(p6+p7)),
// all roundings explicit (no contraction, no reassociation).
__device__ __forceinline__ float pairwise8_sq(const float* v) {
    float p[D];
    #pragma unroll
    for (int d = 0; d < D; ++d) p[d] = __fmul_rn(v[d], v[d]);
    return __fadd_rn(
        __fadd_rn(__fadd_rn(p[0], p[1]), __fadd_rn(p[2], p[3])),
        __fadd_rn(__fadd_rn(p[4], p[5]), __fadd_rn(p[6], p[7])));
}

__global__ __launch_bounds__(BLOCK) void vq_main(
        const float* __restrict__ z,
        const float* __restrict__ cb,
        float* __restrict__ zq,
        float* __restrict__ part_sum,          // [GRID]
        unsigned int* __restrict__ part_hist,  // [K][GRID]
        int n)
{
    __shared__ float cb_s[K * D];              // epilogue gather only
    __shared__ float c2_s[K];
    __shared__ unsigned int h_s[K];
    __shared__ float wsum[NWAVE];

    const int tid = threadIdx.x;
    if (tid < K * D) cb_s[tid] = cb[tid];
    if (tid < K) h_s[tid] = 0u;
    __syncthreads();
    if (tid < K) c2_s[tid] = pairwise8_sq(&cb_s[tid * D]);  // np.sum(cb*cb,1)
    __syncthreads();

    // block owns 1024 contiguous rows; thread owns base+{0,256,512,768}
    const int base = blockIdx.x * (BLOCK * ROWS) + tid;

    // load 4 rows (coalesced float4) and pack row-pairs for v_pk_fma_f32
    v2f zp01[D], zp23[D];
    float z2r[ROWS];
    {
        float zr[ROWS][D];
        #pragma unroll
        for (int r = 0; r < ROWS; ++r) {
            const float4* zp = (const float4*)(z + (size_t)(base + r * BLOCK) * D);
            float4 a = zp[0];
            float4 b = zp[1];
            zr[r][0]=a.x; zr[r][1]=a.y; zr[r][2]=a.z; zr[r][3]=a.w;
            zr[r][4]=b.x; zr[r][5]=b.y; zr[r][6]=b.z; zr[r][7]=b.w;
            z2r[r] = pairwise8_sq(zr[r]);      // np.sum(z*z,1)
        }
        #pragma unroll
        for (int d = 0; d < D; ++d) {
            zp01[d] = (v2f){zr[0][d], zr[1][d]};
            zp23[d] = (v2f){zr[2][d], zr[3][d]};
        }
    }

    float best[ROWS];
    int   bidx[ROWS];
    #pragma unroll
    for (int r = 0; r < ROWS; ++r) { best[r] = 3.4e38f; bidx[r] = 0; }

    const v2f z2_01 = {z2r[0], z2r[1]};
    const v2f z2_23 = {z2r[2], z2r[3]};

    // k-loop: cb read with wave-uniform index -> s_load into SGPRs (no LDS,
    // no VMEM per lane); dot chains packed 2 rows/reg via v_pk_fma_f32
    // (each half is IEEE fp32 fma == scalar chain, bit-exact).
    #pragma unroll 4
    for (int k = 0; k < K; ++k) {
        v2f d01 = {0.f, 0.f}, d23 = {0.f, 0.f};
        #pragma unroll
        for (int d = 0; d < D; ++d) {
            const float cd = cb[k * D + d];    // uniform -> SGPR operand
            const v2f cv = {cd, cd};
            d01 = __builtin_elementwise_fma(zp01[d], cv, d01);
            d23 = __builtin_elementwise_fma(zp23[d], cv, d23);
        }
        const float c2 = c2_s[k];
        v2f dist01, dist23;
        {
            // exactly (z2 - 2*dot) + c2: mul, sub, add — no contraction
            #pragma clang fp contract(off)
            dist01 = (z2_01 - 2.0f * d01) + c2;
            dist23 = (z2_23 - 2.0f * d23) + c2;
        }
        const float dv[ROWS] = {dist01.x, dist01.y, dist23.x, dist23.y};
        #pragma unroll
        for (int r = 0; r < ROWS; ++r)
            if (dv[r] < best[r]) { best[r] = dv[r]; bidx[r] = k; }  // first-index ties
    }

    float lsum = 0.f;
    const float zsc[ROWS][D] = {
        {zp01[0].x, zp01[1].x, zp01[2].x, zp01[3].x, zp01[4].x, zp01[5].x, zp01[6].x, zp01[7].x},
        {zp01[0].y, zp01[1].y, zp01[2].y, zp01[3].y, zp01[4].y, zp01[5].y, zp01[6].y, zp01[7].y},
        {zp23[0].x, zp23[1].x, zp23[2].x, zp23[3].x, zp23[4].x, zp23[5].x, zp23[6].x, zp23[7].x},
        {zp23[0].y, zp23[1].y, zp23[2].y, zp23[3].y, zp23[4].y, zp23[5].y, zp23[6].y, zp23[7].y}};
    #pragma unroll
    for (int r = 0; r < ROWS; ++r) {
        atomicAdd(&h_s[bidx[r]], 1u);
        float o[D];
        #pragma unroll
        for (int d = 0; d < D; ++d) {
            float cq   = cb_s[bidx[r] * D + d];     // LDS gather (divergent idx)
            float diff = __fsub_rn(cq, zsc[r][d]);  // (z_q - z)
            lsum += diff * diff;
            o[d] = __fadd_rn(zsc[r][d], diff);      // z + (z_q - z): ST rounding
        }
        vf4* op = (vf4*)(zq + (size_t)(base + r * BLOCK) * D);
        vf4 o0 = {o[0], o[1], o[2], o[3]};
        vf4 o1 = {o[4], o[5], o[6], o[7]};
        __builtin_nontemporal_store(o0, op);        // z_q never re-read
        __builtin_nontemporal_store(o1, op + 1);
    }

    // wave(64) shuffle reduction of squared-error sum
    #pragma unroll
    for (int off = 32; off > 0; off >>= 1)
        lsum += __shfl_down(lsum, off, 64);
    if ((tid & 63) == 0) wsum[tid >> 6] = lsum;
    __syncthreads();
    if (tid == 0) {
        float t = 0.f;
        #pragma unroll
        for (int w = 0; w < NWAVE; ++w) t += wsum[w];
        part_sum[blockIdx.x] = t;
    }
    if (tid < K) part_hist[(size_t)tid * GRID + blockIdx.x] = h_s[tid];
}

__global__ __launch_bounds__(1024) void vq_final(
        const float* __restrict__ part_sum,
        const unsigned int* __restrict__ part_hist,
        float* __restrict__ out, long long nd, int n)
{
    __shared__ double red[16];
    __shared__ unsigned int hsum[K];
    __shared__ double ent_s[K];
    const int tid = threadIdx.x;

    // total squared error: 2048 partials, f64 accumulate
    double s = 0.0;
    for (int i = tid; i < GRID; i += 1024) s += (double)part_sum[i];
    #pragma unroll
    for (int off = 32; off > 0; off >>= 1) s += __shfl_down(s, off, 64);
    if ((tid & 63) == 0) red[tid >> 6] = s;

    // histogram: 32 threads per bin k, coalesced strided loads, subgroup reduce
    {
        const int k = tid >> 5, j = tid & 31;
        const unsigned int* p = part_hist + (size_t)k * GRID;
        unsigned int c = 0;
        for (int i = j; i < GRID; i += 32) c += p[i];
        #pragma unroll
        for (int off = 16; off > 0; off >>= 1) c += __shfl_down(c, off, 32);
        if (j == 0) hsum[k] = c;
    }
    __syncthreads();

    if (tid < K) {
        double p = (double)hsum[tid] / (double)n;
        ent_s[tid] = p * log(p + 1e-10);
    }
    __syncthreads();

    if (tid == 0) {
        double S = 0.0;
        #pragma unroll
        for (int w = 0; w < 16; ++w) S += red[w];
        double ent = 0.0;
        for (int k = 0; k < K; ++k) ent += ent_s[k];
        out[nd]     = (float)(1.25 * S / (double)nd);
        out[nd + 1] = (float)exp(-ent);
    }
}

extern "C" void kernel_launch(void* const* d_in, const int* in_sizes, int n_in,
                              void* d_out, int out_size, void* d_ws, size_t ws_size,
                              hipStream_t stream)
{
    const float* z  = (const float*)d_in[0];
    const float* cb = (const float*)d_in[1];
    float* out      = (float*)d_out;

    const int n = in_sizes[0] / D;             // 2,097,152 == GRID*BLOCK*ROWS
    const long long nd = (long long)n * D;

    // ws layout: [0, GRID*4) float part_sum; [8192, +K*GRID*4) uint part_hist
    float*        part_sum  = (float*)d_ws;
    unsigned int* part_hist = (unsigned int*)((char*)d_ws + 8192);

    vq_main<<<GRID, BLOCK, 0, stream>>>(z, cb, out, part_sum, part_hist, n);
    vq_final<<<1, 1024, 0, stream>>>(part_sum, part_hist, out, nd, n);
}

// Round 9
// 133.631 us; speedup vs baseline: 1.0036x; 1.0036x over previous
//
#include <hip/hip_runtime.h>
#include <math.h>

#define D 8
#define K 32
constexpr int BLOCK = 256;
constexpr int ROWS  = 4;                       // rows per thread
constexpr int GRID  = 2048;                    // GRID*BLOCK*ROWS == N
constexpr int NWAVE = BLOCK / 64;

typedef float vf4 __attribute__((ext_vector_type(4)));
typedef float v2f __attribute__((ext_vector_type(2)));

// numpy pairwise-sum tree for n=8: ((p0+p1)+(p2+p3))+((p4+p5)+(p6+p7)),
// all roundings explicit (no contraction, no reassociation).
__device__ __forceinline__ float pairwise8_sq(const float* v) {
    float p[D];
    #pragma unroll
    for (int d = 0; d < D; ++d) p[d] = __fmul_rn(v[d], v[d]);
    return __fadd_rn(
        __fadd_rn(__fadd_rn(p[0], p[1]), __fadd_rn(p[2], p[3])),
        __fadd_rn(__fadd_rn(p[4], p[5]), __fadd_rn(p[6], p[7])));
}

__global__ __launch_bounds__(BLOCK) void vq_main(
        const float* __restrict__ z,
        const float* __restrict__ cb,
        float* __restrict__ zq,
        float* __restrict__ part_sum,          // [GRID]
        unsigned int* __restrict__ part_hist,  // [K][GRID]
        int n)
{
    __shared__ float cb_s[K * D];              // epilogue gather only
    __shared__ float c2_s[K];
    __shared__ unsigned int h_s[K];
    __shared__ float wsum[NWAVE];

    const int tid = threadIdx.x;
    if (tid < K * D) cb_s[tid] = cb[tid];
    if (tid < K) h_s[tid] = 0u;
    __syncthreads();
    if (tid < K) c2_s[tid] = pairwise8_sq(&cb_s[tid * D]);  // np.sum(cb*cb,1)
    __syncthreads();

    // block owns 1024 contiguous rows; thread owns base+{0,256,512,768}
    const int base = blockIdx.x * (BLOCK * ROWS) + tid;

    // load 4 rows (coalesced float4) and pack row-pairs for v_pk_fma_f32
    v2f zp01[D], zp23[D];
    float z2r[ROWS];
    {
        float zr[ROWS][D];
        #pragma unroll
        for (int r = 0; r < ROWS; ++r) {
            const float4* zp = (const float4*)(z + (size_t)(base + r * BLOCK) * D);
            float4 a = zp[0];
            float4 b = zp[1];
            zr[r][0]=a.x; zr[r][1]=a.y; zr[r][2]=a.z; zr[r][3]=a.w;
            zr[r][4]=b.x; zr[r][5]=b.y; zr[r][6]=b.z; zr[r][7]=b.w;
            z2r[r] = pairwise8_sq(zr[r]);      // np.sum(z*z,1)
        }
        #pragma unroll
        for (int d = 0; d < D; ++d) {
            zp01[d] = (v2f){zr[0][d], zr[1][d]};
            zp23[d] = (v2f){zr[2][d], zr[3][d]};
        }
    }

    float best[ROWS];
    int   bidx[ROWS];
    #pragma unroll
    for (int r = 0; r < ROWS; ++r) { best[r] = 3.4e38f; bidx[r] = 0; }

    const v2f z2_01 = {z2r[0], z2r[1]};
    const v2f z2_23 = {z2r[2], z2r[3]};

    // k-loop: cb read with wave-uniform index -> s_load into SGPRs; dot
    // chains packed 2 rows/reg via v_pk_fma_f32 (each half IEEE == scalar
    // chain, bit-exact).
    #pragma unroll 4
    for (int k = 0; k < K; ++k) {
        v2f d01 = {0.f, 0.f}, d23 = {0.f, 0.f};
        #pragma unroll
        for (int d = 0; d < D; ++d) {
            const float cd = cb[k * D + d];    // uniform -> SGPR operand
            const v2f cv = {cd, cd};
            d01 = __builtin_elementwise_fma(zp01[d], cv, d01);
            d23 = __builtin_elementwise_fma(zp23[d], cv, d23);
        }
        const float c2 = c2_s[k];
        v2f dist01, dist23;
        {
            // exactly (z2 - 2*dot) + c2: mul, sub, add — no contraction
            #pragma clang fp contract(off)
            dist01 = (z2_01 - 2.0f * d01) + c2;
            dist23 = (z2_23 - 2.0f * d23) + c2;
        }
        const float dv[ROWS] = {dist01.x, dist01.y, dist23.x, dist23.y};
        #pragma unroll
        for (int r = 0; r < ROWS; ++r)
            if (dv[r] < best[r]) { best[r] = dv[r]; bidx[r] = k; }  // first-index ties
    }

    float lsum = 0.f;
    const float zsc[ROWS][D] = {
        {zp01[0].x, zp01[1].x, zp01[2].x, zp01[3].x, zp01[4].x, zp01[5].x, zp01[6].x, zp01[7].x},
        {zp01[0].y, zp01[1].y, zp01[2].y, zp01[3].y, zp01[4].y, zp01[5].y, zp01[6].y, zp01[7].y},
        {zp23[0].x, zp23[1].x, zp23[2].x, zp23[3].x, zp23[4].x, zp23[5].x, zp23[6].x, zp23[7].x},
        {zp23[0].y, zp23[1].y, zp23[2].y, zp23[3].y, zp23[4].y, zp23[5].y, zp23[6].y, zp23[7].y}};
    #pragma unroll
    for (int r = 0; r < ROWS; ++r) {
        atomicAdd(&h_s[bidx[r]], 1u);
        float o[D];
        #pragma unroll
        for (int d = 0; d < D; ++d) {
            float cq   = cb_s[bidx[r] * D + d];     // LDS gather (divergent idx)
            float diff = __fsub_rn(cq, zsc[r][d]);  // (z_q - z)
            lsum += diff * diff;
            o[d] = __fadd_rn(zsc[r][d], diff);      // z + (z_q - z): ST rounding
        }
        // PLAIN stores (R8 used nontemporal): the two 16 B halves per lane
        // interleave at 32 B stride — L2 merges them into full lines before
        // HBM eviction; NT streamed half-line partials at ~half write BW.
        vf4* op = (vf4*)(zq + (size_t)(base + r * BLOCK) * D);
        vf4 o0 = {o[0], o[1], o[2], o[3]};
        vf4 o1 = {o[4], o[5], o[6], o[7]};
        op[0] = o0;
        op[1] = o1;
    }

    // wave(64) shuffle reduction of squared-error sum
    #pragma unroll
    for (int off = 32; off > 0; off >>= 1)
        lsum += __shfl_down(lsum, off, 64);
    if ((tid & 63) == 0) wsum[tid >> 6] = lsum;
    __syncthreads();
    if (tid == 0) {
        float t = 0.f;
        #pragma unroll
        for (int w = 0; w < NWAVE; ++w) t += wsum[w];
        part_sum[blockIdx.x] = t;
    }
    if (tid < K) part_hist[(size_t)tid * GRID + blockIdx.x] = h_s[tid];
}

__global__ __launch_bounds__(1024) void vq_final(
        const float* __restrict__ part_sum,
        const unsigned int* __restrict__ part_hist,
        float* __restrict__ out, long long nd, int n)
{
    __shared__ double red[16];
    __shared__ unsigned int hsum[K];
    __shared__ double ent_s[K];
    const int tid = threadIdx.x;

    // total squared error: 2048 partials, f64 accumulate
    double s = 0.0;
    for (int i = tid; i < GRID; i += 1024) s += (double)part_sum[i];
    #pragma unroll
    for (int off = 32; off > 0; off >>= 1) s += __shfl_down(s, off, 64);
    if ((tid & 63) == 0) red[tid >> 6] = s;

    // histogram: 32 threads per bin k, coalesced strided loads, subgroup reduce
    {
        const int k = tid >> 5, j = tid & 31;
        const unsigned int* p = part_hist + (size_t)k * GRID;
        unsigned int c = 0;
        for (int i = j; i < GRID; i += 32) c += p[i];
        #pragma unroll
        for (int off = 16; off > 0; off >>= 1) c += __shfl_down(c, off, 32);
        if (j == 0) hsum[k] = c;
    }
    __syncthreads();

    if (tid < K) {
        double p = (double)hsum[tid] / (double)n;
        ent_s[tid] = p * log(p + 1e-10);
    }
    __syncthreads();

    if (tid == 0) {
        double S = 0.0;
        #pragma unroll
        for (int w = 0; w < 16; ++w) S += red[w];
        double ent = 0.0;
        for (int k = 0; k < K; ++k) ent += ent_s[k];
        out[nd]     = (float)(1.25 * S / (double)nd);
        out[nd + 1] = (float)exp(-ent);
    }
}

extern "C" void kernel_launch(void* const* d_in, const int* in_sizes, int n_in,
                              void* d_out, int out_size, void* d_ws, size_t ws_size,
                              hipStream_t stream)
{
    const float* z  = (const float*)d_in[0];
    const float* cb = (const float*)d_in[1];
    float* out      = (float*)d_out;

    const int n = in_sizes[0] / D;             // 2,097,152 == GRID*BLOCK*ROWS
    const long long nd = (long long)n * D;

    // ws layout: [0, GRID*4) float part_sum; [8192, +K*GRID*4) uint part_hist
    float*        part_sum  = (float*)d_ws;
    unsigned int* part_hist = (unsigned int*)((char*)d_ws + 8192);

    vq_main<<<GRID, BLOCK, 0, stream>>>(z, cb, out, part_sum, part_hist, n);
    vq_final<<<1, 1024, 0, stream>>>(part_sum, part_hist, out, nd, n);
}

// Round 10
// 129.455 us; speedup vs baseline: 1.0359x; 1.0323x over previous
//
#include <hip/hip_runtime.h>
#include <math.h>

#define D 8
#define K 32
constexpr int BLOCK = 256;
constexpr int ROWS  = 2;                       // rows per thread (packed in one v2f)
constexpr int GRID  = 4096;                    // GRID*BLOCK*ROWS == N; 2 residency tranches/CU
constexpr int NWAVE = BLOCK / 64;

typedef float vf4 __attribute__((ext_vector_type(4)));
typedef float v2f __attribute__((ext_vector_type(2)));

// numpy pairwise-sum tree for n=8: ((p0+p1)+(p2+p3))+((p4+p5)+(p6+p7)),
// all roundings explicit (no contraction, no reassociation).
__device__ __forceinline__ float pairwise8_sq(const float* v) {
    float p[D];
    #pragma unroll
    for (int d = 0; d < D; ++d) p[d] = __fmul_rn(v[d], v[d]);
    return __fadd_rn(
        __fadd_rn(__fadd_rn(p[0], p[1]), __fadd_rn(p[2], p[3])),
        __fadd_rn(__fadd_rn(p[4], p[5]), __fadd_rn(p[6], p[7])));
}

__global__ __launch_bounds__(BLOCK) void vq_main(
        const float* __restrict__ z,
        const float* __restrict__ cb,
        float* __restrict__ zq,
        float* __restrict__ part_sum,          // [GRID]
        unsigned int* __restrict__ part_hist,  // [K][GRID]
        int n)
{
    __shared__ float cb_s[K * D];              // epilogue gather only
    __shared__ float c2_s[K];
    __shared__ unsigned int h_s[K];
    __shared__ float wsum[NWAVE];

    const int tid = threadIdx.x;
    if (tid < K * D) cb_s[tid] = cb[tid];
    if (tid < K) h_s[tid] = 0u;
    __syncthreads();
    if (tid < K) c2_s[tid] = pairwise8_sq(&cb_s[tid * D]);  // np.sum(cb*cb,1)
    __syncthreads();

    // block owns 512 contiguous rows; thread owns base and base+256
    const int base = blockIdx.x * (BLOCK * ROWS) + tid;

    // load 2 rows (coalesced float4) and pack them for v_pk_fma_f32
    v2f zp01[D];
    float z2r[ROWS];
    {
        float zr[ROWS][D];
        #pragma unroll
        for (int r = 0; r < ROWS; ++r) {
            const float4* zp = (const float4*)(z + (size_t)(base + r * BLOCK) * D);
            float4 a = zp[0];
            float4 b = zp[1];
            zr[r][0]=a.x; zr[r][1]=a.y; zr[r][2]=a.z; zr[r][3]=a.w;
            zr[r][4]=b.x; zr[r][5]=b.y; zr[r][6]=b.z; zr[r][7]=b.w;
            z2r[r] = pairwise8_sq(zr[r]);      // np.sum(z*z,1)
        }
        #pragma unroll
        for (int d = 0; d < D; ++d)
            zp01[d] = (v2f){zr[0][d], zr[1][d]};
    }

    float best[ROWS];
    int   bidx[ROWS];
    #pragma unroll
    for (int r = 0; r < ROWS; ++r) { best[r] = 3.4e38f; bidx[r] = 0; }

    const v2f z2_01 = {z2r[0], z2r[1]};

    // k-loop: cb read with wave-uniform index -> s_load into SGPRs; dot
    // chain packed 2 rows/reg via v_pk_fma_f32 (each half IEEE == scalar
    // chain, bit-exact).
    #pragma unroll 4
    for (int k = 0; k < K; ++k) {
        v2f d01 = {0.f, 0.f};
        #pragma unroll
        for (int d = 0; d < D; ++d) {
            const float cd = cb[k * D + d];    // uniform -> SGPR operand
            d01 = __builtin_elementwise_fma(zp01[d], (v2f){cd, cd}, d01);
        }
        const float c2 = c2_s[k];
        v2f dist01;
        {
            // exactly (z2 - 2*dot) + c2: mul, sub, add — no contraction
            #pragma clang fp contract(off)
            dist01 = (z2_01 - 2.0f * d01) + c2;
        }
        const float dv[ROWS] = {dist01.x, dist01.y};
        #pragma unroll
        for (int r = 0; r < ROWS; ++r)
            if (dv[r] < best[r]) { best[r] = dv[r]; bidx[r] = k; }  // first-index ties
    }

    float lsum = 0.f;
    const float zsc[ROWS][D] = {
        {zp01[0].x, zp01[1].x, zp01[2].x, zp01[3].x, zp01[4].x, zp01[5].x, zp01[6].x, zp01[7].x},
        {zp01[0].y, zp01[1].y, zp01[2].y, zp01[3].y, zp01[4].y, zp01[5].y, zp01[6].y, zp01[7].y}};
    #pragma unroll
    for (int r = 0; r < ROWS; ++r) {
        atomicAdd(&h_s[bidx[r]], 1u);
        float o[D];
        #pragma unroll
        for (int d = 0; d < D; ++d) {
            float cq   = cb_s[bidx[r] * D + d];     // LDS gather (divergent idx)
            float diff = __fsub_rn(cq, zsc[r][d]);  // (z_q - z)
            lsum += diff * diff;
            o[d] = __fadd_rn(zsc[r][d], diff);      // z + (z_q - z): ST rounding
        }
        // plain stores: L2 merges the 32 B-stride interleaved halves into
        // full lines (R9 verified WRITE_SIZE at ideal 67 MB)
        vf4* op = (vf4*)(zq + (size_t)(base + r * BLOCK) * D);
        op[0] = (vf4){o[0], o[1], o[2], o[3]};
        op[1] = (vf4){o[4], o[5], o[6], o[7]};
    }

    // wave(64) shuffle reduction of squared-error sum
    #pragma unroll
    for (int off = 32; off > 0; off >>= 1)
        lsum += __shfl_down(lsum, off, 64);
    if ((tid & 63) == 0) wsum[tid >> 6] = lsum;
    __syncthreads();
    if (tid == 0) {
        float t = 0.f;
        #pragma unroll
        for (int w = 0; w < NWAVE; ++w) t += wsum[w];
        part_sum[blockIdx.x] = t;
    }
    if (tid < K) part_hist[(size_t)tid * GRID + blockIdx.x] = h_s[tid];
}

__global__ __launch_bounds__(1024) void vq_final(
        const float* __restrict__ part_sum,
        const unsigned int* __restrict__ part_hist,
        float* __restrict__ out, long long nd, int n)
{
    __shared__ double red[16];
    __shared__ unsigned int hsum[K];
    __shared__ double ent_s[K];
    const int tid = threadIdx.x;

    // total squared error: GRID partials, f64 accumulate
    double s = 0.0;
    for (int i = tid; i < GRID; i += 1024) s += (double)part_sum[i];
    #pragma unroll
    for (int off = 32; off > 0; off >>= 1) s += __shfl_down(s, off, 64);
    if ((tid & 63) == 0) red[tid >> 6] = s;

    // histogram: 32 threads per bin k, coalesced strided loads, subgroup reduce
    {
        const int k = tid >> 5, j = tid & 31;
        const unsigned int* p = part_hist + (size_t)k * GRID;
        unsigned int c = 0;
        for (int i = j; i < GRID; i += 32) c += p[i];
        #pragma unroll
        for (int off = 16; off > 0; off >>= 1) c += __shfl_down(c, off, 32);
        if (j == 0) hsum[k] = c;
    }
    __syncthreads();

    if (tid < K) {
        double p = (double)hsum[tid] / (double)n;
        ent_s[tid] = p * log(p + 1e-10);
    }
    __syncthreads();

    if (tid == 0) {
        double S = 0.0;
        #pragma unroll
        for (int w = 0; w < 16; ++w) S += red[w];
        double ent = 0.0;
        for (int k = 0; k < K; ++k) ent += ent_s[k];
        out[nd]     = (float)(1.25 * S / (double)nd);
        out[nd + 1] = (float)exp(-ent);
    }
}

extern "C" void kernel_launch(void* const* d_in, const int* in_sizes, int n_in,
                              void* d_out, int out_size, void* d_ws, size_t ws_size,
                              hipStream_t stream)
{
    const float* z  = (const float*)d_in[0];
    const float* cb = (const float*)d_in[1];
    float* out      = (float*)d_out;

    const int n = in_sizes[0] / D;             // 2,097,152 == GRID*BLOCK*ROWS
    const long long nd = (long long)n * D;

    // ws layout: [0, GRID*4) float part_sum; [32768, +K*GRID*4) uint part_hist
    float*        part_sum  = (float*)d_ws;
    unsigned int* part_hist = (unsigned int*)((char*)d_ws + 32768);

    vq_main<<<GRID, BLOCK, 0, stream>>>(z, cb, out, part_sum, part_hist, n);
    vq_final<<<1, 1024, 0, stream>>>(part_sum, part_hist, out, nd, n);
}